// Round 14
// baseline (507.071 us; speedup 1.0000x reference)
//
#include <hip/hip_runtime.h>
#include <hip/hip_fp16.h>

#define NBLK 256
#define FPAD 16   // 64 B per flag slot

typedef _Float16 h2_t __attribute__((ext_vector_type(2)));

#define AG_LD(p)    __hip_atomic_load((p), __ATOMIC_RELAXED, __HIP_MEMORY_SCOPE_AGENT)
#define AG_ST(p, v) __hip_atomic_store((p), (v), __ATOMIC_RELAXED, __HIP_MEMORY_SCOPE_AGENT)

__device__ __forceinline__ unsigned pkh(float a, float b) {
    const __half2 h = __floats2half2_rn(a, b);
    return __builtin_bit_cast(unsigned, h);
}
__device__ __forceinline__ float fdot2(unsigned w, unsigned a, float c) {
#if __has_builtin(__builtin_amdgcn_fdot2)
    return __builtin_amdgcn_fdot2(__builtin_bit_cast(h2_t, w),
                                  __builtin_bit_cast(h2_t, a), c, false);
#else
    const float2 fw = __half22float2(__builtin_bit_cast(__half2, w));
    const float2 fa = __half22float2(__builtin_bit_cast(__half2, a));
    return c + fw.x * fa.x + fw.y * fa.y;
#endif
}

// Packed fp16 weights: octet g=k>>3; WtH[m*32768 + g*1024 + c*4 + ((k>>1)&3)]
// mats: 0-2 aggW[i], 3-5 C1[i]=W1*aggW, 6-8 CU1[i]=U1*aggW, 9-11 U2[i]
__device__ __forceinline__ uint4 wld(const unsigned* __restrict__ WtH,
                                     int m, int g, int c) {
    return *(const uint4*)(WtH + (size_t)m * 32768 + (size_t)g * 1024 + c * 4);
}

// Global fan-out barrier (validated R5-R13). fence only after P0.
__device__ __forceinline__ void gridbar(int n, unsigned* flags, unsigned* rel,
                                        int bid, bool fence) {
    __syncthreads();
    if (threadIdx.x == 0)
        __hip_atomic_store(&flags[bid * FPAD], (unsigned)n, __ATOMIC_RELEASE,
                           __HIP_MEMORY_SCOPE_AGENT);
    if (bid == 0) {
        if (threadIdx.x < NBLK) {
            while ((int)__hip_atomic_load(&flags[threadIdx.x * FPAD],
                                          __ATOMIC_RELAXED,
                                          __HIP_MEMORY_SCOPE_AGENT) < n)
                __builtin_amdgcn_s_sleep(1);
        }
        __syncthreads();
        if (threadIdx.x < 16)
            __hip_atomic_store(&rel[(n * 16 + threadIdx.x) * FPAD], (unsigned)n,
                               __ATOMIC_RELEASE, __HIP_MEMORY_SCOPE_AGENT);
    } else {
        if (threadIdx.x == 0) {
            while ((int)__hip_atomic_load(&rel[(n * 16 + (bid & 15)) * FPAD],
                                          __ATOMIC_RELAXED,
                                          __HIP_MEMORY_SCOPE_AGENT) < n)
                __builtin_amdgcn_s_sleep(1);
        }
    }
    if (fence) __builtin_amdgcn_fence(__ATOMIC_ACQUIRE, "agent");
    __syncthreads();
}

// Per-batch softmax combine + sigmoid + U2 matvec + updB (validated R12).
__device__ __forceinline__ float phaseB(int i, int b, int c, int rq, int tid,
                                        const float* __restrict__ part,
                                        const unsigned* __restrict__ WtH,
                                        const float* __restrict__ updB,
                                        float* sc, float* aggl32,
                                        unsigned* aggh) {
    float M = -1e30f, den = 0.f, num = 0.f;
    const int par = i & 1;
    #pragma unroll
    for (int j = rq * 8; j < rq * 8 + 8; ++j) {
        const float* pp = part + (size_t)(par * 256 + b * 16 + j) * 768;
        const float mj = AG_LD(pp + c);
        const float dj = AG_LD(pp + 256 + c);
        const float nj = AG_LD(pp + 512 + c);
        const float Mn = fmaxf(M, mj);
        const float s = __expf(M - Mn), e = __expf(mj - Mn);
        den = den * s + dj * e;
        num = num * s + nj * e;
        M = Mn;
    }
    sc[rq * 256 + c] = M;
    sc[512 + rq * 256 + c] = den;
    sc[1024 + rq * 256 + c] = num;
    __syncthreads();
    if (rq == 0) {
        const float m0 = sc[c], m1 = sc[256 + c];
        const float Mx = fmaxf(m0, m1);
        const float s0 = __expf(m0 - Mx), s1 = __expf(m1 - Mx);
        const float dd = sc[512 + c] * s0 + sc[768 + c] * s1;
        const float nn = sc[1024 + c] * s0 + sc[1280 + c] * s1;
        aggl32[c] = 1.f / (1.f + __expf(-(nn / dd)));
    }
    __syncthreads();
    if (tid < 128) aggh[tid] = pkh(aggl32[2 * tid], aggl32[2 * tid + 1]);
    __syncthreads();
    const int g0 = rq * 16;
    uint4 buf[8];
    #pragma unroll
    for (int j = 0; j < 8; ++j) buf[j] = wld(WtH, 9 + i, g0 + j, c);
    float au = 0.f;
    #pragma unroll
    for (int ph = 0; ph < 2; ++ph) {
        #pragma unroll
        for (int j = 0; j < 8; ++j) {
            const uint4 w = buf[j];
            if (ph < 1) buf[j] = wld(WtH, 9 + i, g0 + 8 + j, c);
            const uint4 a = *(const uint4*)&aggh[(g0 + ph * 8 + j) * 4];
            au = fdot2(w.x, a.x, au);
            au = fdot2(w.y, a.y, au);
            au = fdot2(w.z, a.z, au);
            au = fdot2(w.w, a.w, au);
        }
    }
    __syncthreads();
    sc[rq * 256 + c] = au;
    __syncthreads();
    return sc[c] + sc[256 + c] + updB[i * 256 + c];
}

__global__ __launch_bounds__(512, 2) void fused_k(
    const float* __restrict__ feat,   // [16][128][256]
    const float* __restrict__ mask,   // [16][128]
    const float* __restrict__ aggW,   // [3][256][256]
    const float* __restrict__ aggB,   // [3][256]
    const float* __restrict__ attnW,  // [3][256][512]
    const float* __restrict__ updW,   // [3][256][512]
    const float* __restrict__ updB,   // [3][256]
    unsigned* __restrict__ WtH,       // 12 * 32768 uints, packed fp16
    float* __restrict__ part,         // 2 * 256 * 768
    float* __restrict__ bias1,        // [3][256] = W1@aggB
    float* __restrict__ biasU1,       // [3][256] = U1@aggB
    unsigned* flags, unsigned* rel,
    float* __restrict__ out)
{
    __shared__ __align__(16) float ldsf[9608];
    unsigned* hidh   = (unsigned*)ldsf;           // [0,1024)    8r x 128 pairs
    float*    xu32   = ldsf + 1024;               // [1024,3072) 8 x 256
    float*    red    = ldsf + 3072;               // [3072,9216) 24 x 256
    float*    sc     = red;                       // phaseB overlay (1536)
    float*    aggl32 = ldsf + 9216;               // [9216,9472)
    unsigned* aggh   = (unsigned*)ldsf + 9472;    // [9472,9600)
    float*    msk    = ldsf + 9600;               // [9600,9608)

    const int bid = blockIdx.x;
    const int tid = threadIdx.x;
    const int c  = tid & 255;
    const int rq = tid >> 8;                  // 0..1, wave-uniform
    const int b  = bid >> 4, jj = bid & 15;
    const int row0 = b * 128 + jj * 8;

    // ---- P0a: stage hid0 = fp16(feat*mask) + mask (LDS survives the fence)
    #pragma unroll
    for (int it = 0; it < 2; ++it) {
        const int j = it * 512 + tid, r = j >> 7, pr = j & 127;
        const float2 f = *(const float2*)(feat + (size_t)(row0 + r) * 256 + pr * 2);
        const float mv = mask[row0 + r];
        hidh[r * 128 + pr] = pkh(f.x * mv, f.y * mv);
    }
    if (tid < 8) msk[tid] = mask[row0 + tid];

    // ---- P0b: build the 12 packed matrices (blocks 0..191)
    if (bid < 192) {
        const int m = bid >> 4, t = bid & 15, tr = t >> 2, tc = t & 3;
        if (m < 3 || m >= 9) {
            // transpose+pack aggW (m<3) / U2 = updW[:,256:] (m>=9)
            float (*Tl)[65] = (float (*)[65])(ldsf + 1024);
            const float* src; int stride, off;
            if (m < 3) { src = aggW + (size_t)m * 65536;        stride = 256; off = 0;   }
            else       { src = updW + (size_t)(m - 9) * 131072; stride = 512; off = 256; }
            unsigned* dstu = WtH + (size_t)m * 32768;
            #pragma unroll
            for (int it = 0; it < 2; ++it) {
                const int j = it * 512 + tid, row = j >> 4, q = (j & 15) * 4;
                const float4 v = *(const float4*)(src + (size_t)(tr * 64 + row) * stride + off + tc * 64 + q);
                Tl[row][q + 0] = v.x; Tl[row][q + 1] = v.y;
                Tl[row][q + 2] = v.z; Tl[row][q + 3] = v.w;
            }
            __syncthreads();
            #pragma unroll
            for (int it = 0; it < 4; ++it) {
                const int j = it * 512 + tid, cl = j >> 5, pr = j & 31;
                const unsigned val = pkh(Tl[cl][pr * 2], Tl[cl][pr * 2 + 1]);
                const int P = tc * 32 + pr, g = P >> 2, jq = P & 3;
                dstu[(size_t)g * 1024 + (tr * 64 + cl) * 4 + jq] = val;
            }
        } else {
            // C1[i] = W1@aggW (m 3..5) / CU1[i] = U1@aggW (m 6..8), + biases
            const int ii = (m < 6) ? m - 3 : m - 6;
            const float* M1 = ((m < 6) ? attnW : updW) + (size_t)ii * 131072; // [j][512]
            const float* Ag = aggW + (size_t)ii * 65536;                       // [t][256]
            const float* Bg = aggB + ii * 256;
            float (*Al)[65] = (float (*)[65])(ldsf + 1024);   // [1024,5184)
            float (*Bl)[68] = (float (*)[68])(ldsf + 5184);   // [5184,9536)
            const int jl = tid >> 3, kg = tid & 7;
            float acc[8] = {};
            float bacc = 0.f;
            for (int cc = 0; cc < 4; ++cc) {
                __syncthreads();
                {
                    const int rr = tid >> 3, q = (tid & 7) * 8;
                    const float* s1 = M1 + (size_t)(tr * 64 + rr) * 512 + cc * 64 + q;
                    const float4 a0 = *(const float4*)s1;
                    const float4 a1 = *(const float4*)(s1 + 4);
                    Al[rr][q + 0] = a0.x; Al[rr][q + 1] = a0.y;
                    Al[rr][q + 2] = a0.z; Al[rr][q + 3] = a0.w;
                    Al[rr][q + 4] = a1.x; Al[rr][q + 5] = a1.y;
                    Al[rr][q + 6] = a1.z; Al[rr][q + 7] = a1.w;
                    const float* s2 = Ag + (size_t)(cc * 64 + rr) * 256 + tc * 64 + q;
                    const float4 b0 = *(const float4*)s2;
                    const float4 b1q = *(const float4*)(s2 + 4);
                    Bl[rr][q + 0] = b0.x; Bl[rr][q + 1] = b0.y;
                    Bl[rr][q + 2] = b0.z; Bl[rr][q + 3] = b0.w;
                    Bl[rr][q + 4] = b1q.x; Bl[rr][q + 5] = b1q.y;
                    Bl[rr][q + 6] = b1q.z; Bl[rr][q + 7] = b1q.w;
                }
                __syncthreads();
                #pragma unroll 8
                for (int tt = 0; tt < 64; ++tt) {
                    const float a = Al[jl][tt];
                    const float4 w0 = *(const float4*)&Bl[tt][kg * 8];
                    const float4 w1 = *(const float4*)&Bl[tt][kg * 8 + 4];
                    acc[0] += a * w0.x; acc[1] += a * w0.y;
                    acc[2] += a * w0.z; acc[3] += a * w0.w;
                    acc[4] += a * w1.x; acc[5] += a * w1.y;
                    acc[6] += a * w1.z; acc[7] += a * w1.w;
                    bacc += a * Bg[cc * 64 + tt];
                }
            }
            uint4 o;
            o.x = pkh(acc[0], acc[1]); o.y = pkh(acc[2], acc[3]);
            o.z = pkh(acc[4], acc[5]); o.w = pkh(acc[6], acc[7]);
            *(uint4*)(WtH + (size_t)m * 32768 + (size_t)(tc * 8 + kg) * 1024
                      + (tr * 64 + jl) * 4) = o;
            if (tc == 0 && kg == 0) {
                float* bdst = (m < 6) ? bias1 : biasU1;
                bdst[ii * 256 + tr * 64 + jl] = bacc;
            }
        }
    }
    gridbar(1, flags, rel, bid, true);   // only fenced barrier

    for (int i = 0; i < 3; ++i) {
        if (i > 0) {
            const float accU = phaseB(i - 1, b, c, rq, tid, part, WtH, updB,
                                      sc, aggl32, aggh);
            __syncthreads();             // protect sc(=red) reuse
            if (rq == 1) {
                #pragma unroll
                for (int r = 0; r < 8; ++r)
                    red[r * 256 + c] = (xu32[r * 256 + c] + accU) * msk[r];
            }
            __syncthreads();
            #pragma unroll
            for (int it = 0; it < 2; ++it) {
                const int j = it * 512 + tid, r = j >> 7, pr = j & 127;
                hidh[r * 128 + pr] = pkh(red[r * 256 + pr * 2],
                                         red[r * 256 + pr * 2 + 1]);
            }
            __syncthreads();
        }

        // ---- fused GEMM: x, p, xu1 all from hid, 3 streams, k-split by rq
        float accx[8] = {}, accp[8] = {}, accu[8] = {};
        {
            const int g0 = rq * 16;
            uint4 bA[2], bB[2], bC[2];
            bA[0] = wld(WtH, i,     g0, c); bA[1] = wld(WtH, i,     g0 + 1, c);
            bB[0] = wld(WtH, 3 + i, g0, c); bB[1] = wld(WtH, 3 + i, g0 + 1, c);
            bC[0] = wld(WtH, 6 + i, g0, c); bC[1] = wld(WtH, 6 + i, g0 + 1, c);
            #pragma unroll
            for (int g = 0; g < 16; ++g) {
                const int s = g & 1;
                const uint4 wa = bA[s], wb = bB[s], wc = bC[s];
                if (g < 14) {
                    bA[s] = wld(WtH, i,     g0 + g + 2, c);
                    bB[s] = wld(WtH, 3 + i, g0 + g + 2, c);
                    bC[s] = wld(WtH, 6 + i, g0 + g + 2, c);
                }
                #pragma unroll
                for (int r = 0; r < 8; ++r) {
                    const uint4 h = *(const uint4*)&hidh[r * 128 + (g0 + g) * 4];
                    accx[r] = fdot2(wa.x, h.x, accx[r]);
                    accx[r] = fdot2(wa.y, h.y, accx[r]);
                    accx[r] = fdot2(wa.z, h.z, accx[r]);
                    accx[r] = fdot2(wa.w, h.w, accx[r]);
                    accp[r] = fdot2(wb.x, h.x, accp[r]);
                    accp[r] = fdot2(wb.y, h.y, accp[r]);
                    accp[r] = fdot2(wb.z, h.z, accp[r]);
                    accp[r] = fdot2(wb.w, h.w, accp[r]);
                    accu[r] = fdot2(wc.x, h.x, accu[r]);
                    accu[r] = fdot2(wc.y, h.y, accu[r]);
                    accu[r] = fdot2(wc.z, h.z, accu[r]);
                    accu[r] = fdot2(wc.w, h.w, accu[r]);
                }
            }
        }
        // cross-half reduce: rq1 publishes x,p parts; rq0 publishes u part
        if (rq == 1) {
            #pragma unroll
            for (int r = 0; r < 8; ++r) {
                red[r * 256 + c]       = accx[r];
                red[(8 + r) * 256 + c] = accp[r];
            }
        } else {
            #pragma unroll
            for (int r = 0; r < 8; ++r) red[(16 + r) * 256 + c] = accu[r];
        }
        __syncthreads();
        if (rq == 0) {
            const float bb = aggB[i * 256 + c];
            const float b1v = bias1[i * 256 + c];
            float xr[8], pr8[8];
            #pragma unroll
            for (int r = 0; r < 8; ++r) {
                xr[r]  = accx[r] + red[r * 256 + c] + bb;
                pr8[r] = accp[r] + red[(8 + r) * 256 + c] + b1v;
            }
            float m8 = pr8[0];
            #pragma unroll
            for (int r = 1; r < 8; ++r) m8 = fmaxf(m8, pr8[r]);
            float d8 = 0.f, n8 = 0.f;
            #pragma unroll
            for (int r = 0; r < 8; ++r) {
                const float e = __expf(pr8[r] - m8);
                d8 += e;
                n8 += e * xr[r];
            }
            float* pb = part + (size_t)((i & 1) * 256 + bid) * 768;
            AG_ST(pb + c, m8);
            AG_ST(pb + 256 + c, d8);
            AG_ST(pb + 512 + c, n8);
        } else {
            const float buv = biasU1[i * 256 + c];
            #pragma unroll
            for (int r = 0; r < 8; ++r)
                xu32[r * 256 + c] = accu[r] + red[(16 + r) * 256 + c] + buv;
        }
        gridbar(i + 2, flags, rel, bid, false);   // no fence: L2 stays warm
    }

    // ---- final combine + epilogue: out = xU1 + accU
    const float accU = phaseB(2, b, c, rq, tid, part, WtH, updB, sc, aggl32, aggh);
    if (rq == 1) {
        #pragma unroll
        for (int r = 0; r < 8; ++r)
            out[(size_t)(row0 + r) * 256 + c] = xu32[r * 256 + c] + accU;
    }
}

extern "C" void kernel_launch(void* const* d_in, const int* in_sizes, int n_in,
                              void* d_out, int out_size, void* d_ws, size_t ws_size,
                              hipStream_t stream) {
    const float* feat  = (const float*)d_in[0];
    const float* mask  = (const float*)d_in[1];
    const float* aggW  = (const float*)d_in[2];
    const float* aggB  = (const float*)d_in[3];
    const float* attnW = (const float*)d_in[4];
    // d_in[5] = attnB: cancels in softmax (constant along the s axis)
    const float* updW  = (const float*)d_in[6];
    const float* updB  = (const float*)d_in[7];

    unsigned* WtH = (unsigned*)d_ws;                   // 12 * 32768 uints
    float* part   = (float*)(WtH + 12 * 32768);        // 2 * 256 * 768
    float* bias1  = part + 2 * 256 * 768;              // 3 * 256
    float* biasU1 = bias1 + 768;                       // 3 * 256
    unsigned* flags = (unsigned*)(biasU1 + 768);
    unsigned* rel   = flags + NBLK * FPAD;

    fused_k<<<NBLK, 512, 0, stream>>>(
        feat, mask, aggW, aggB, attnW, updW, updB,
        WtH, part, bias1, biasU1, flags, rel, (float*)d_out);
}